// Round 1
// baseline (438.007 us; speedup 1.0000x reference)
//
#include <hip/hip_runtime.h>

#define B_ROWS 4096
#define T_LEN  8192
#define GAMMA  0.99f
#define COEF   0.9405f   /* 0.99 * 0.95 */
#define CHUNK  256       /* 64 lanes * 4 elements */

__global__ __launch_bounds__(256) void gae_kernel(
    const float* __restrict__ rewards,
    const float* __restrict__ values,
    float* __restrict__ adv,
    float* __restrict__ tgt)
{
    const int wid  = (int)((blockIdx.x * blockDim.x + threadIdx.x) >> 6);
    const int lane = (int)(threadIdx.x & 63);
    if (wid >= B_ROWS) return;

    const float* r_row = rewards + (size_t)wid * T_LEN;
    const float* v_row = values  + (size_t)wid * (T_LEN + 1);
    float* a_row = adv + (size_t)wid * T_LEN;
    float* t_row = tgt + (size_t)wid * T_LEN;

    const float c4 = COEF * COEF * COEF * COEF;

    float carry = 0.0f;                 // A at t0+CHUNK for the current chunk
    float v_next_first = v_row[T_LEN];  // V[t0+CHUNK] for the current chunk

    // Load first (latest-in-time) chunk
    int t0 = T_LEN - CHUNK;
    {
        // nothing: loads done inside loop via "current" regs initialized here
    }
    int base = t0 + 4 * lane;
    float4 rv = *(const float4*)(r_row + base);
    float v0 = v_row[base + 0];
    float v1 = v_row[base + 1];
    float v2 = v_row[base + 2];
    float v3 = v_row[base + 3];

    for (; t0 >= 0; t0 -= CHUNK) {
        // ---- prefetch next (earlier-in-time) chunk ----
        float4 rvn = make_float4(0.f, 0.f, 0.f, 0.f);
        float n0 = 0.f, n1 = 0.f, n2 = 0.f, n3 = 0.f;
        const int tn = t0 - CHUNK;
        if (tn >= 0) {
            const int bn = tn + 4 * lane;
            rvn = *(const float4*)(r_row + bn);
            n0 = v_row[bn + 0];
            n1 = v_row[bn + 1];
            n2 = v_row[bn + 2];
            n3 = v_row[bn + 3];
        }

        // ---- V_{t+1} for the lane's last element ----
        float v4 = __shfl_down(v0, 1);
        if (lane == 63) v4 = v_next_first;

        // ---- deltas ----
        const float d0 = fmaf(GAMMA, v1, rv.x) - v0;
        const float d1 = fmaf(GAMMA, v2, rv.y) - v1;
        const float d2 = fmaf(GAMMA, v3, rv.z) - v2;
        const float d3 = fmaf(GAMMA, v4, rv.w) - v3;

        // ---- in-lane suffix scan with zero carry: P_i = a0 ----
        const float a3l = d3;
        const float a2l = fmaf(COEF, a3l, d2);
        const float a1l = fmaf(COEF, a2l, d1);
        const float a0l = fmaf(COEF, a1l, d0);

        // ---- wave suffix composition of affines h_i(x) = P_i + c^4 * x ----
        // After scan, lane i holds G_i = h_i ∘ ... ∘ h_63 as (a, b).
        float a = a0l;
        float b = c4;
        #pragma unroll
        for (int dlt = 1; dlt < 64; dlt <<= 1) {
            const float ar = __shfl_down(a, dlt);
            const float br = __shfl_down(b, dlt);
            if (lane + dlt < 64) {
                a = fmaf(b, ar, a);
                b = b * br;
            }
        }
        const float A0_aff = fmaf(b, carry, a);   // A at position 4i (given chunk carry)

        // lane carry-in: A at position 4(i+1)
        float cl = __shfl_down(A0_aff, 1);
        if (lane == 63) cl = carry;

        // ---- exact in-lane chain with real carry ----
        const float A3 = fmaf(COEF, cl, d3);
        const float A2 = fmaf(COEF, A3, d2);
        const float A1 = fmaf(COEF, A2, d1);
        const float A0 = fmaf(COEF, A1, d0);

        // ---- stores (row stride 8192 floats -> 16B aligned) ----
        *(float4*)(a_row + t0 + 4 * lane) = make_float4(A0, A1, A2, A3);
        *(float4*)(t_row + t0 + 4 * lane) =
            make_float4(v0 + A0, v1 + A1, v2 + A2, v3 + A3);

        // ---- propagate carries to the next (earlier) chunk ----
        carry        = __shfl(A0, 0);   // A at t0
        v_next_first = __shfl(v0, 0);   // V at t0

        // ---- rotate prefetch ----
        rv = rvn;
        v0 = n0; v1 = n1; v2 = n2; v3 = n3;
    }
}

extern "C" void kernel_launch(void* const* d_in, const int* in_sizes, int n_in,
                              void* d_out, int out_size, void* d_ws, size_t ws_size,
                              hipStream_t stream) {
    const float* rewards = (const float*)d_in[0];
    const float* values  = (const float*)d_in[1];
    float* adv = (float*)d_out;                       // advantages [B, T]
    float* tgt = adv + (size_t)B_ROWS * T_LEN;        // targets    [B, T]

    const int threads = 256;                          // 4 waves/block
    const int blocks  = (B_ROWS * 64) / threads;      // one wave per row
    gae_kernel<<<blocks, threads, 0, stream>>>(rewards, values, adv, tgt);
}

// Round 2
// 431.976 us; speedup vs baseline: 1.0140x; 1.0140x over previous
//
#include <hip/hip_runtime.h>

#define B_ROWS 4096
#define T_LEN  8192
#define GAMMA  0.99f
#define COEF   0.9405f   /* 0.99 * 0.95 */
#define CHUNK  256       /* 64 lanes * 4 elements */
#define SEG    1024      /* independent segment length (c^256=1.5e-7 halo truncation) */
#define HALO   256       /* halo length, multiple of CHUNK */
#define NSEG   (T_LEN / SEG)

__device__ __forceinline__ float bcast0(float x) {
    return __uint_as_float(__builtin_amdgcn_readfirstlane(__float_as_uint(x)));
}

__global__ __launch_bounds__(256) void gae_kernel(
    const float* __restrict__ rewards,
    const float* __restrict__ values,
    float* __restrict__ adv,
    float* __restrict__ tgt)
{
    const int gw   = (int)((blockIdx.x * blockDim.x + threadIdx.x) >> 6);
    const int lane = (int)(threadIdx.x & 63);
    const int row  = gw >> 3;          // NSEG = 8 segments per row
    const int seg  = gw & 7;
    if (row >= B_ROWS) return;

    const int s0       = seg * SEG;
    const int halo_end = min(s0 + SEG + HALO, T_LEN);

    const float* r_row = rewards + (size_t)row * T_LEN;
    const float* v_row = values  + (size_t)row * (T_LEN + 1);
    float* a_row = adv + (size_t)row * T_LEN;
    float* t_row = tgt + (size_t)row * T_LEN;

    const float c4 = COEF * COEF * COEF * COEF;

    float carry        = 0.0f;             // truncated: exact for last segment
    float v_next_first = v_row[halo_end];  // V at the first element past this chunk

    int t0 = halo_end - CHUNK;
    int base = t0 + 4 * lane;
    float4 rv = *(const float4*)(r_row + base);
    float v0 = v_row[base + 0];
    float v1 = v_row[base + 1];
    float v2 = v_row[base + 2];
    float v3 = v_row[base + 3];

    for (; t0 >= s0; t0 -= CHUNK) {
        // ---- prefetch next (earlier-in-time) chunk ----
        float4 rvn = make_float4(0.f, 0.f, 0.f, 0.f);
        float n0 = 0.f, n1 = 0.f, n2 = 0.f, n3 = 0.f;
        const int tn = t0 - CHUNK;
        if (tn >= s0) {
            const int bn = tn + 4 * lane;
            rvn = *(const float4*)(r_row + bn);
            n0 = v_row[bn + 0];
            n1 = v_row[bn + 1];
            n2 = v_row[bn + 2];
            n3 = v_row[bn + 3];
        }

        // ---- V_{t+1} for the lane's last element ----
        float v4 = __shfl_down(v0, 1);
        if (lane == 63) v4 = v_next_first;

        // ---- deltas ----
        const float d0 = fmaf(GAMMA, v1, rv.x) - v0;
        const float d1 = fmaf(GAMMA, v2, rv.y) - v1;
        const float d2 = fmaf(GAMMA, v3, rv.z) - v2;
        const float d3 = fmaf(GAMMA, v4, rv.w) - v3;

        // ---- in-lane suffix scan with zero carry ----
        const float a3l = d3;
        const float a2l = fmaf(COEF, a3l, d2);
        const float a1l = fmaf(COEF, a2l, d1);
        const float a0l = fmaf(COEF, a1l, d0);

        // ---- wave suffix composition of affines h_i(x) = P_i + c^4 * x ----
        float a = a0l;
        float b = c4;
        #pragma unroll
        for (int dlt = 1; dlt < 64; dlt <<= 1) {
            const float ar = __shfl_down(a, dlt);
            const float br = __shfl_down(b, dlt);
            if (lane + dlt < 64) {
                a = fmaf(b, ar, a);
                b = b * br;
            }
        }
        const float A0_aff = fmaf(b, carry, a);

        // lane carry-in: A at position 4(i+1)
        float cl = __shfl_down(A0_aff, 1);
        if (lane == 63) cl = carry;

        // ---- exact in-lane chain with real carry ----
        const float A3 = fmaf(COEF, cl, d3);
        const float A2 = fmaf(COEF, A3, d2);
        const float A1 = fmaf(COEF, A2, d1);
        const float A0 = fmaf(COEF, A1, d0);

        // ---- stores: only inside the owned segment (halo chunks skipped) ----
        if (t0 < s0 + SEG) {
            *(float4*)(a_row + t0 + 4 * lane) = make_float4(A0, A1, A2, A3);
            *(float4*)(t_row + t0 + 4 * lane) =
                make_float4(v0 + A0, v1 + A1, v2 + A2, v3 + A3);
        }

        // ---- propagate carries (scalar broadcast, off the DS critical path) ----
        carry        = bcast0(A0);
        v_next_first = bcast0(v0);

        // ---- rotate prefetch ----
        rv = rvn;
        v0 = n0; v1 = n1; v2 = n2; v3 = n3;
    }
}

extern "C" void kernel_launch(void* const* d_in, const int* in_sizes, int n_in,
                              void* d_out, int out_size, void* d_ws, size_t ws_size,
                              hipStream_t stream) {
    const float* rewards = (const float*)d_in[0];
    const float* values  = (const float*)d_in[1];
    float* adv = (float*)d_out;                       // advantages [B, T]
    float* tgt = adv + (size_t)B_ROWS * T_LEN;        // targets    [B, T]

    const int threads = 256;                          // 4 waves/block
    const int total_waves = B_ROWS * NSEG;            // one wave per (row, segment)
    const int blocks  = (total_waves * 64) / threads; // 8192 blocks
    gae_kernel<<<blocks, threads, 0, stream>>>(rewards, values, adv, tgt);
}